// Round 9
// baseline (749.197 us; speedup 1.0000x reference)
//
#include <hip/hip_runtime.h>

static constexpr int B_ = 8;
static constexpr int N_ = 16384;
static constexpr int D_ = 256;
static constexpr int L_ = 64;

static constexpr int TPB = 512;       // 256 WGs x 512 thr, 1 WG/CU (LDS-forced), 1 point/thread
static constexpr int LF4 = 18;        // dims 0..71 in LDS
static constexpr int RF4 = 64 - LF4;  // dims 72..255 in VGPRs (46 float4)

// ws layout (init zeroes 208896 B every call; ws poisoned 0xAA once):
//   slot u64[8][64][32] @ 0       (131072 B)  packed (val_bits<<32)|(~n) per WG per step
//   pay  u32[8][64][32] @ 131072  ( 65536 B)  xn_bits^0x80000000 of that candidate
//   wwin u64[8][64]     @ 196608  (  4096 B)  winner (enc<<32)|idx per step (master-published)
//   gadj u32[8][128]    @ 200704  (  4096 B)  64x64 edge bitmask per batch
//   cnt  u32[8]         @ 204800  (    32 B)  finalize arrival counters

__global__ void __launch_bounds__(1024)
init_kernel(unsigned int* __restrict__ z)
{
    z[blockIdx.x * 1024 + threadIdx.x] = 0u;   // grid 51 -> 208896 B
}

// ---------------------------------------------------------------------------
// Fused FPS scan + witness + finalize. Hierarchical per-batch barrier:
//   all 32 WGs publish (pay, vmcnt(0), key) — r8-proven;
//   ONLY master WG (wib 0) polls the 32 slots, max-reduces (same keys ->
//   same winner as r8), publishes one packed u64 to wwin[b][s];
//   other WGs poll that single uniform address (1 broadcast req per poll).
// All FMA/compare orders bit-identical to the r5..r8-validated kernels.
// ---------------------------------------------------------------------------
__global__ __attribute__((amdgpu_flat_work_group_size(512, 512),
                          amdgpu_waves_per_eu(2, 2)))
void fps_all_kernel(const float* __restrict__ emb, const float* __restrict__ csp,
                    unsigned long long* __restrict__ slot,
                    unsigned int* __restrict__ pay,
                    unsigned long long* __restrict__ wwin,
                    unsigned int* __restrict__ gadj,
                    unsigned int* __restrict__ cnt,
                    float* __restrict__ out)
{
    const int wg  = blockIdx.x;        // 0..255
    const int b   = wg >> 5;           // batch (32 WGs/batch)
    const int wib = wg & 31;
    const int tid = threadIdx.x;
    const int n   = (wib << 9) + tid;  // my point
    const float c = fabsf(csp[0]);

    __shared__ float4 slab[LF4 * TPB];          // 147456 B resident slice
    __shared__ __align__(16) float lmbuf[D_];
    __shared__ float wval[8];
    __shared__ int   widx[8];
    __shared__ float wxn[8];
    __shared__ int   s_next;
    __shared__ float s_lmn;
    __shared__ int   s_lead;
    __shared__ unsigned int lmask[128];
    __shared__ int   labels[64];

    if (tid < 128) lmask[tid] = 0u;

    const float4* __restrict__ pt = (const float4*)(emb + (size_t)(b * N_ + n) * D_);

    // resident load + norm (sequential 4-acc over k=0..63, matches r1..r8)
    float4 p[RF4];
    float s0 = 0.f, s1 = 0.f, s2 = 0.f, s3 = 0.f;
    #pragma unroll
    for (int k = 0; k < LF4; ++k) {
        float4 v = pt[k];
        slab[k * TPB + tid] = v;
        s0 = fmaf(v.x, v.x, s0); s1 = fmaf(v.y, v.y, s1);
        s2 = fmaf(v.z, v.z, s2); s3 = fmaf(v.w, v.w, s3);
    }
    #pragma unroll
    for (int k = 0; k < RF4; ++k) {
        float4 v = pt[LF4 + k];
        p[k] = v;
        s0 = fmaf(v.x, v.x, s0); s1 = fmaf(v.y, v.y, s1);
        s2 = fmaf(v.z, v.z, s2); s3 = fmaf(v.w, v.w, s3);
    }
    const float my_xn = (s0 + s1) + (s2 + s3);

    float min_d = __builtin_inff();
    float b1v = __builtin_inff(), b2v = __builtin_inff();
    int   b1i = 0, b2i = 0;
    int   lm    = 0;      // landmark 0 = point 0
    float lmn_c = 0.f;

    #pragma unroll 1
    for (int s = 1; s <= L_; ++s) {
        // stage row of landmark position s-1 (index lm)
        if (tid < 64)
            ((float4*)lmbuf)[tid] =
                ((const float4*)(emb + (size_t)(b * N_ + lm) * D_))[tid];
        __syncthreads();

        float lmn;
        if (s == 1) {
            // landmark 0's norm computed locally (r6/r8-validated, same op order)
            const float4* l4 = (const float4*)lmbuf;
            float t0 = 0.f, t1 = 0.f, t2 = 0.f, t3 = 0.f;
            #pragma unroll
            for (int k = 0; k < 64; ++k) {
                float4 w = l4[k];
                t0 = fmaf(w.x, w.x, t0); t1 = fmaf(w.y, w.y, t1);
                t2 = fmaf(w.z, w.z, t2); t3 = fmaf(w.w, w.w, t3);
            }
            lmn = (t0 + t1) + (t2 + t3);
        } else {
            lmn = lmn_c;   // winner's xn carried through the barrier (r5/r8-validated)
        }

        const float4* __restrict__ w4 = (const float4*)lmbuf;
        float d0 = 0.f, d1 = 0.f, d2 = 0.f, d3 = 0.f;
        #pragma unroll
        for (int k = 0; k < LF4; ++k) {
            float4 v = slab[k * TPB + tid];
            float4 w = w4[k];
            d0 = fmaf(v.x, w.x, d0); d1 = fmaf(v.y, w.y, d1);
            d2 = fmaf(v.z, w.z, d2); d3 = fmaf(v.w, w.w, d3);
        }
        #pragma unroll
        for (int k = 0; k < RF4; ++k) {
            float4 v = p[k];
            float4 w = w4[LF4 + k];
            d0 = fmaf(v.x, w.x, d0); d1 = fmaf(v.y, w.y, d1);
            d2 = fmaf(v.z, w.z, d2); d3 = fmaf(v.w, w.w, d3);
        }
        const float dot  = (d0 + d1) + (d2 + d3);
        const float diff = fmaxf(my_xn + lmn - 2.f * dot, 1e-10f);
        const float fac  = fmaxf(1.f + c * my_xn + c * lmn, 1e-6f);
        const float d    = sqrtf(diff) * sqrtf(fac);

        // fused witness: landmark POSITION s-1, ascending order, strict '<'
        if (d < b1v)      { b2v = b1v; b2i = b1i; b1v = d; b1i = s - 1; }
        else if (d < b2v) { b2v = d; b2i = s - 1; }

        if (s == L_) break;

        min_d = fminf(min_d, d);

        // wave argmax (tie -> lower n), carrying candidate's xn
        float v = min_d; int i = n; float x = my_xn;
        #pragma unroll
        for (int off = 32; off >= 1; off >>= 1) {
            float ov = __shfl_down(v, off);
            int   oi = __shfl_down(i, off);
            float ox = __shfl_down(x, off);
            if (ov > v || (ov == v && oi < i)) { v = ov; i = oi; x = ox; }
        }
        if ((tid & 63) == 0) {
            const int w = tid >> 6;
            wval[w] = v; widx[w] = i; wxn[w] = x;
        }
        __syncthreads();

        if (tid < 64) {   // wave 0 only
            v = (tid < 8) ? wval[tid] : -__builtin_inff();
            i = (tid < 8) ? widx[tid] : 0x7FFFFFFF;
            x = (tid < 8) ? wxn[tid]  : 0.f;
            #pragma unroll
            for (int off = 4; off >= 1; off >>= 1) {
                float ov = __shfl_down(v, off);
                int   oi = __shfl_down(i, off);
                float ox = __shfl_down(x, off);
                if (ov > v || (ov == v && oi < i)) { v = ov; i = oi; x = ox; }
            }
            const int base = (b * 64 + s) * 32;
            if (tid == 0) {   // publish my WG's candidate (r8-proven ordering)
                const unsigned long long key =
                    ((unsigned long long)__float_as_uint(v) << 32) |
                    (unsigned long long)(0xFFFFFFFFu - (unsigned)i);
                const unsigned enc = __float_as_uint(x) ^ 0x80000000u;  // never 0
                __hip_atomic_store(&pay[base + wib], enc,
                                   __ATOMIC_RELAXED, __HIP_MEMORY_SCOPE_AGENT);
                asm volatile("s_waitcnt vmcnt(0)" ::: "memory");
                __hip_atomic_store(&slot[base + wib], key,
                                   __ATOMIC_RELAXED, __HIP_MEMORY_SCOPE_AGENT);
            }

            if (wib == 0) {
                // master: poll all 32 candidate slots, reduce, publish winner
                unsigned long long myk; unsigned mye;
                for (;;) {
                    myk = __hip_atomic_load(&slot[base + (tid & 31)],
                                            __ATOMIC_RELAXED, __HIP_MEMORY_SCOPE_AGENT);
                    mye = __hip_atomic_load(&pay[base + (tid & 31)],
                                            __ATOMIC_RELAXED, __HIP_MEMORY_SCOPE_AGENT);
                    if (__all((myk != 0ull) && (mye != 0u))) break;
                    __builtin_amdgcn_s_sleep(1);
                }
                unsigned long long k = myk; unsigned e = mye;
                #pragma unroll
                for (int off = 32; off >= 1; off >>= 1) {
                    unsigned long long ok = __shfl_down(k, off);
                    unsigned           oe = __shfl_down(e, off);
                    if (ok > k) { k = ok; e = oe; }
                }
                if (tid == 0) {
                    const unsigned wn = 0xFFFFFFFFu - (unsigned)(k & 0xFFFFFFFFull);
                    __hip_atomic_store(&wwin[b * 64 + s],
                                       ((unsigned long long)e << 32) | wn,
                                       __ATOMIC_RELAXED, __HIP_MEMORY_SCOPE_AGENT);
                    s_next = (int)wn;
                    s_lmn  = __uint_as_float(e ^ 0x80000000u);
                }
            } else {
                // non-master: poll single uniform address (1 broadcast req/poll)
                unsigned long long w;
                for (;;) {
                    w = __hip_atomic_load(&wwin[b * 64 + s],
                                          __ATOMIC_RELAXED, __HIP_MEMORY_SCOPE_AGENT);
                    if (w != 0ull) break;
                    __builtin_amdgcn_s_sleep(1);
                }
                if (tid == 0) {
                    s_next = (int)(unsigned)(w & 0xFFFFFFFFull);
                    s_lmn  = __uint_as_float((unsigned)(w >> 32) ^ 0x80000000u);
                }
            }
        }
        __syncthreads();
        lm    = s_next;
        lmn_c = s_lmn;
    }

    // emit my edge (top-2 landmark positions) into LDS bitmask
    {
        const int lo = min(b1i, b2i), hi = max(b1i, b2i);
        const int bitpos = lo * 64 + hi;
        atomicOr(&lmask[bitpos >> 5], 1u << (bitpos & 31));
    }
    __syncthreads();
    if (tid < 128) {
        unsigned w = lmask[tid];
        if (w) atomicOr(&gadj[b * 128 + tid], w);   // agent-scope RMW at LLC
    }
    __syncthreads();

    if (tid == 0) {
        __threadfence();
        unsigned prev = atomicAdd(&cnt[b], 1u);
        s_lead = (prev == 31u) ? 1 : 0;
    }
    __syncthreads();
    if (!s_lead) return;

    // ---- leader WG (last arriver): finalize this batch ----
    __threadfence();
    if (tid < 128) lmask[tid] = atomicOr(&gadj[b * 128 + tid], 0u);  // coherent read
    __syncthreads();

    unsigned long long m = 0ull;
    if (tid < 64) {
        m = ((unsigned long long)lmask[tid * 2 + 1] << 32) | lmask[tid * 2];
        for (int j = 0; j < 64; ++j)           // symmetrize: column bits
            if (lmask[j * 2 + (tid >> 5)] & (1u << (tid & 31))) m |= 1ull << j;
        labels[tid] = tid;
    }
    __syncthreads();

    for (int it = 0; it < 64; ++it) {          // synchronous min-label propagation
        int mn = 0;
        if (tid < 64) {
            mn = labels[tid];
            unsigned long long mm = m;
            while (mm) {
                int j = __ffsll(mm) - 1;
                int lj = labels[j];
                mn = mn < lj ? mn : lj;
                mm &= mm - 1;
            }
        }
        __syncthreads();
        if (tid < 64) labels[tid] = mn;
        __syncthreads();
    }

    if (tid < 64) {
        unsigned long long hi_mask = (tid < 63) ? (~0ull << (tid + 1)) : 0ull;
        int myedges = __popcll(m & hi_mask);
        int mycomp  = (labels[tid] == tid) ? 1 : 0;
        #pragma unroll
        for (int off = 32; off >= 1; off >>= 1) {
            myedges += __shfl_down(myedges, off);
            mycomp  += __shfl_down(mycomp, off);
        }
        if (tid == 0) {
            float beta0 = (float)mycomp;
            float beta1 = (float)(myedges - (64 - mycomp));
            out[b]      = beta0;
            out[8 + b]  = beta1;
            out[16 + b] = beta0 / 64.f;
            out[24 + b] = (beta1 > 3.f) ? 1.f : 0.f;
        }
    }
}

// ---------------------------------------------------------------------------
extern "C" void kernel_launch(void* const* d_in, const int* in_sizes, int n_in,
                              void* d_out, int out_size, void* d_ws, size_t ws_size,
                              hipStream_t stream)
{
    const float* emb = (const float*)d_in[0];
    const float* cs  = (const float*)d_in[1];
    float* out = (float*)d_out;

    char* ws = (char*)d_ws;
    unsigned long long* slot = (unsigned long long*)(ws);
    unsigned int*       pay  = (unsigned int*)(ws + 131072);
    unsigned long long* wwin = (unsigned long long*)(ws + 196608);
    unsigned int*       gadj = (unsigned int*)(ws + 200704);
    unsigned int*       cnt  = (unsigned int*)(ws + 204800);

    hipLaunchKernelGGL(init_kernel, dim3(51), dim3(1024), 0, stream,
                       (unsigned int*)ws);
    hipLaunchKernelGGL(fps_all_kernel, dim3(256), dim3(TPB), 0, stream,
                       emb, cs, slot, pay, wwin, gadj, cnt, out);
}

// Round 10
// 621.426 us; speedup vs baseline: 1.2056x; 1.2056x over previous
//
#include <hip/hip_runtime.h>

static constexpr int B_ = 8;
static constexpr int N_ = 16384;
static constexpr int D_ = 256;
static constexpr int L_ = 64;

static constexpr int TPB = 512;       // 256 WGs x 512 thr, 1 WG/CU (LDS-forced), 1 point/thread
static constexpr int LF4 = 18;        // dims 0..71 in LDS
static constexpr int RF4 = 64 - LF4;  // dims 72..255 in VGPRs (46 float4)

// ws layout (init zeroes 208896 B every call; ws poisoned 0xAA once):
//   slot u64[8][64][32] @ 0       (131072 B)  packed (val_bits<<32)|(~n) per WG per step
//   pay  u32[8][64][32] @ 131072  ( 65536 B)  xn_bits^0x80000000 of that candidate
//   wwin u64[8][64]     @ 196608  (  4096 B)  winner (enc<<32)|idx per step (master-published)
//   gadj u32[8][128]    @ 200704  (  4096 B)  64x64 edge bitmask per batch
//   cnt  u32[8]         @ 204800  (    32 B)  finalize arrival counters

__global__ void __launch_bounds__(1024)
init_kernel(unsigned int* __restrict__ z)
{
    z[blockIdx.x * 1024 + threadIdx.x] = 0u;   // grid 51 -> 208896 B
}

// ---------------------------------------------------------------------------
// Fused FPS scan + witness + finalize. r9 structure, ONE change: the landmark
// row is read directly from global memory through a readfirstlane-uniform
// address (scalar-cache path; wave-broadcast L1 at worst) instead of being
// staged into LDS and re-read 64x per thread per step. Values and FMA order
// are bit-identical to r5..r9 (same memory, same accumulation sequence).
// ---------------------------------------------------------------------------
__global__ __attribute__((amdgpu_flat_work_group_size(512, 512),
                          amdgpu_waves_per_eu(2, 2)))
void fps_all_kernel(const float* __restrict__ emb, const float* __restrict__ csp,
                    unsigned long long* __restrict__ slot,
                    unsigned int* __restrict__ pay,
                    unsigned long long* __restrict__ wwin,
                    unsigned int* __restrict__ gadj,
                    unsigned int* __restrict__ cnt,
                    float* __restrict__ out)
{
    const int wg  = blockIdx.x;        // 0..255
    const int b   = wg >> 5;           // batch (32 WGs/batch)
    const int wib = wg & 31;
    const int tid = threadIdx.x;
    const int n   = (wib << 9) + tid;  // my point
    const float c = fabsf(csp[0]);

    __shared__ float4 slab[LF4 * TPB];          // 147456 B resident slice
    __shared__ float wval[8];
    __shared__ int   widx[8];
    __shared__ float wxn[8];
    __shared__ int   s_next;
    __shared__ float s_lmn;
    __shared__ int   s_lead;
    __shared__ unsigned int lmask[128];
    __shared__ int   labels[64];

    if (tid < 128) lmask[tid] = 0u;

    const float4* __restrict__ pt = (const float4*)(emb + (size_t)(b * N_ + n) * D_);

    // resident load + norm (sequential 4-acc over k=0..63, matches r1..r9)
    float4 p[RF4];
    float s0 = 0.f, s1 = 0.f, s2 = 0.f, s3 = 0.f;
    #pragma unroll
    for (int k = 0; k < LF4; ++k) {
        float4 v = pt[k];
        slab[k * TPB + tid] = v;
        s0 = fmaf(v.x, v.x, s0); s1 = fmaf(v.y, v.y, s1);
        s2 = fmaf(v.z, v.z, s2); s3 = fmaf(v.w, v.w, s3);
    }
    #pragma unroll
    for (int k = 0; k < RF4; ++k) {
        float4 v = pt[LF4 + k];
        p[k] = v;
        s0 = fmaf(v.x, v.x, s0); s1 = fmaf(v.y, v.y, s1);
        s2 = fmaf(v.z, v.z, s2); s3 = fmaf(v.w, v.w, s3);
    }
    const float my_xn = (s0 + s1) + (s2 + s3);

    float min_d = __builtin_inff();
    float b1v = __builtin_inff(), b2v = __builtin_inff();
    int   b1i = 0, b2i = 0;
    int   lm    = 0;      // landmark 0 = point 0
    float lmn_c = 0.f;

    #pragma unroll 1
    for (int s = 1; s <= L_; ++s) {
        // uniform (SGPR) pointer to landmark row s-1 — scalar-load candidate
        const int lmU = __builtin_amdgcn_readfirstlane(lm);
        const float4* __restrict__ w4 =
            (const float4*)(emb + (size_t)(b * N_ + lmU) * D_);

        float lmn;
        if (s == 1) {
            // landmark 0's norm computed locally (same 4-acc k-ascending order)
            float t0 = 0.f, t1 = 0.f, t2 = 0.f, t3 = 0.f;
            #pragma unroll
            for (int k = 0; k < 64; ++k) {
                float4 w = w4[k];
                t0 = fmaf(w.x, w.x, t0); t1 = fmaf(w.y, w.y, t1);
                t2 = fmaf(w.z, w.z, t2); t3 = fmaf(w.w, w.w, t3);
            }
            lmn = (t0 + t1) + (t2 + t3);
        } else {
            lmn = lmn_c;   // winner's xn carried through the barrier (r5..r9)
        }

        float d0 = 0.f, d1 = 0.f, d2 = 0.f, d3 = 0.f;
        #pragma unroll
        for (int k = 0; k < LF4; ++k) {
            float4 v = slab[k * TPB + tid];
            float4 w = w4[k];
            d0 = fmaf(v.x, w.x, d0); d1 = fmaf(v.y, w.y, d1);
            d2 = fmaf(v.z, w.z, d2); d3 = fmaf(v.w, w.w, d3);
        }
        #pragma unroll
        for (int k = 0; k < RF4; ++k) {
            float4 v = p[k];
            float4 w = w4[LF4 + k];
            d0 = fmaf(v.x, w.x, d0); d1 = fmaf(v.y, w.y, d1);
            d2 = fmaf(v.z, w.z, d2); d3 = fmaf(v.w, w.w, d3);
        }
        const float dot  = (d0 + d1) + (d2 + d3);
        const float diff = fmaxf(my_xn + lmn - 2.f * dot, 1e-10f);
        const float fac  = fmaxf(1.f + c * my_xn + c * lmn, 1e-6f);
        const float d    = sqrtf(diff) * sqrtf(fac);

        // fused witness: landmark POSITION s-1, ascending order, strict '<'
        if (d < b1v)      { b2v = b1v; b2i = b1i; b1v = d; b1i = s - 1; }
        else if (d < b2v) { b2v = d; b2i = s - 1; }

        if (s == L_) break;

        min_d = fminf(min_d, d);

        // wave argmax (tie -> lower n), carrying candidate's xn
        float v = min_d; int i = n; float x = my_xn;
        #pragma unroll
        for (int off = 32; off >= 1; off >>= 1) {
            float ov = __shfl_down(v, off);
            int   oi = __shfl_down(i, off);
            float ox = __shfl_down(x, off);
            if (ov > v || (ov == v && oi < i)) { v = ov; i = oi; x = ox; }
        }
        if ((tid & 63) == 0) {
            const int w = tid >> 6;
            wval[w] = v; widx[w] = i; wxn[w] = x;
        }
        __syncthreads();

        if (tid < 64) {   // wave 0 only
            v = (tid < 8) ? wval[tid] : -__builtin_inff();
            i = (tid < 8) ? widx[tid] : 0x7FFFFFFF;
            x = (tid < 8) ? wxn[tid]  : 0.f;
            #pragma unroll
            for (int off = 4; off >= 1; off >>= 1) {
                float ov = __shfl_down(v, off);
                int   oi = __shfl_down(i, off);
                float ox = __shfl_down(x, off);
                if (ov > v || (ov == v && oi < i)) { v = ov; i = oi; x = ox; }
            }
            const int base = (b * 64 + s) * 32;
            if (tid == 0) {   // publish my WG's candidate (r8-proven ordering)
                const unsigned long long key =
                    ((unsigned long long)__float_as_uint(v) << 32) |
                    (unsigned long long)(0xFFFFFFFFu - (unsigned)i);
                const unsigned enc = __float_as_uint(x) ^ 0x80000000u;  // never 0
                __hip_atomic_store(&pay[base + wib], enc,
                                   __ATOMIC_RELAXED, __HIP_MEMORY_SCOPE_AGENT);
                asm volatile("s_waitcnt vmcnt(0)" ::: "memory");
                __hip_atomic_store(&slot[base + wib], key,
                                   __ATOMIC_RELAXED, __HIP_MEMORY_SCOPE_AGENT);
            }

            if (wib == 0) {
                // master: poll all 32 candidate slots, reduce, publish winner
                unsigned long long myk; unsigned mye;
                for (;;) {
                    myk = __hip_atomic_load(&slot[base + (tid & 31)],
                                            __ATOMIC_RELAXED, __HIP_MEMORY_SCOPE_AGENT);
                    mye = __hip_atomic_load(&pay[base + (tid & 31)],
                                            __ATOMIC_RELAXED, __HIP_MEMORY_SCOPE_AGENT);
                    if (__all((myk != 0ull) && (mye != 0u))) break;
                    __builtin_amdgcn_s_sleep(1);
                }
                unsigned long long k = myk; unsigned e = mye;
                #pragma unroll
                for (int off = 32; off >= 1; off >>= 1) {
                    unsigned long long ok = __shfl_down(k, off);
                    unsigned           oe = __shfl_down(e, off);
                    if (ok > k) { k = ok; e = oe; }
                }
                if (tid == 0) {
                    const unsigned wn = 0xFFFFFFFFu - (unsigned)(k & 0xFFFFFFFFull);
                    __hip_atomic_store(&wwin[b * 64 + s],
                                       ((unsigned long long)e << 32) | wn,
                                       __ATOMIC_RELAXED, __HIP_MEMORY_SCOPE_AGENT);
                    s_next = (int)wn;
                    s_lmn  = __uint_as_float(e ^ 0x80000000u);
                }
            } else {
                // non-master: poll single uniform address (broadcast req/poll)
                unsigned long long w;
                for (;;) {
                    w = __hip_atomic_load(&wwin[b * 64 + s],
                                          __ATOMIC_RELAXED, __HIP_MEMORY_SCOPE_AGENT);
                    if (w != 0ull) break;
                    __builtin_amdgcn_s_sleep(1);
                }
                if (tid == 0) {
                    s_next = (int)(unsigned)(w & 0xFFFFFFFFull);
                    s_lmn  = __uint_as_float((unsigned)(w >> 32) ^ 0x80000000u);
                }
            }
        }
        __syncthreads();
        lm    = s_next;
        lmn_c = s_lmn;
    }

    // emit my edge (top-2 landmark positions) into LDS bitmask
    {
        const int lo = min(b1i, b2i), hi = max(b1i, b2i);
        const int bitpos = lo * 64 + hi;
        atomicOr(&lmask[bitpos >> 5], 1u << (bitpos & 31));
    }
    __syncthreads();
    if (tid < 128) {
        unsigned w = lmask[tid];
        if (w) atomicOr(&gadj[b * 128 + tid], w);   // agent-scope RMW at LLC
    }
    __syncthreads();

    if (tid == 0) {
        __threadfence();
        unsigned prev = atomicAdd(&cnt[b], 1u);
        s_lead = (prev == 31u) ? 1 : 0;
    }
    __syncthreads();
    if (!s_lead) return;

    // ---- leader WG (last arriver): finalize this batch ----
    __threadfence();
    if (tid < 128) lmask[tid] = atomicOr(&gadj[b * 128 + tid], 0u);  // coherent read
    __syncthreads();

    unsigned long long m = 0ull;
    if (tid < 64) {
        m = ((unsigned long long)lmask[tid * 2 + 1] << 32) | lmask[tid * 2];
        for (int j = 0; j < 64; ++j)           // symmetrize: column bits
            if (lmask[j * 2 + (tid >> 5)] & (1u << (tid & 31))) m |= 1ull << j;
        labels[tid] = tid;
    }
    __syncthreads();

    for (int it = 0; it < 64; ++it) {          // synchronous min-label propagation
        int mn = 0;
        if (tid < 64) {
            mn = labels[tid];
            unsigned long long mm = m;
            while (mm) {
                int j = __ffsll(mm) - 1;
                int lj = labels[j];
                mn = mn < lj ? mn : lj;
                mm &= mm - 1;
            }
        }
        __syncthreads();
        if (tid < 64) labels[tid] = mn;
        __syncthreads();
    }

    if (tid < 64) {
        unsigned long long hi_mask = (tid < 63) ? (~0ull << (tid + 1)) : 0ull;
        int myedges = __popcll(m & hi_mask);
        int mycomp  = (labels[tid] == tid) ? 1 : 0;
        #pragma unroll
        for (int off = 32; off >= 1; off >>= 1) {
            myedges += __shfl_down(myedges, off);
            mycomp  += __shfl_down(mycomp, off);
        }
        if (tid == 0) {
            float beta0 = (float)mycomp;
            float beta1 = (float)(myedges - (64 - mycomp));
            out[b]      = beta0;
            out[8 + b]  = beta1;
            out[16 + b] = beta0 / 64.f;
            out[24 + b] = (beta1 > 3.f) ? 1.f : 0.f;
        }
    }
}

// ---------------------------------------------------------------------------
extern "C" void kernel_launch(void* const* d_in, const int* in_sizes, int n_in,
                              void* d_out, int out_size, void* d_ws, size_t ws_size,
                              hipStream_t stream)
{
    const float* emb = (const float*)d_in[0];
    const float* cs  = (const float*)d_in[1];
    float* out = (float*)d_out;

    char* ws = (char*)d_ws;
    unsigned long long* slot = (unsigned long long*)(ws);
    unsigned int*       pay  = (unsigned int*)(ws + 131072);
    unsigned long long* wwin = (unsigned long long*)(ws + 196608);
    unsigned int*       gadj = (unsigned int*)(ws + 200704);
    unsigned int*       cnt  = (unsigned int*)(ws + 204800);

    hipLaunchKernelGGL(init_kernel, dim3(51), dim3(1024), 0, stream,
                       (unsigned int*)ws);
    hipLaunchKernelGGL(fps_all_kernel, dim3(256), dim3(TPB), 0, stream,
                       emb, cs, slot, pay, wwin, gadj, cnt, out);
}